// Round 1
// baseline (683.287 us; speedup 1.0000x reference)
//
#include <hip/hip_runtime.h>
#include <math.h>

#define NSUBJ 8192
#define NTT   512
#define OBS   9
#define LOG2PI 1.8378770664093453f

__global__ void zero_out_kernel(float* out) { out[0] = 0.0f; }

__global__ __launch_bounds__(64, 1) void rskf_kernel(
    const float* __restrict__ y,        // (N, NT, O)
    const float* __restrict__ b1_r1,    // (3,)
    const float* __restrict__ lam1f,    // (6,)
    const float* __restrict__ q1d,      // (3,)
    const float* __restrict__ b2_in,    // (3,3) row-major
    const float* __restrict__ lam2f,    // (8,)
    const float* __restrict__ q2d,      // (3,)
    const float* __restrict__ r_in,     // (9,)
    const float* __restrict__ g1p,      // (1,)
    const float* __restrict__ g2p,      // (3,)
    const float* __restrict__ g3p,      // (1,)
    const float* __restrict__ g4p,      // (3,)
    float* __restrict__ out)
{
    const int n = blockIdx.x * blockDim.x + threadIdx.x;
    if (n >= NSUBJ) return;

    // ---------------- constants (uniform across threads -> scalar regs) ----------------
    float Rinv[9];
    float logdetR = 0.0f;
    #pragma unroll
    for (int i = 0; i < 9; ++i) {
        float r = fabsf(r_in[i]) + 1e-4f;
        Rinv[i] = 1.0f / r;
        logdetR += __logf(r);
    }

    // Regime 1: B diag, Lam block-diagonal (3 factors x 3 indicators)
    float b1[3] = { b1_r1[0], b1_r1[1], b1_r1[2] };
    float u[9];
    u[0] = 1.0f; u[1] = lam1f[0]; u[2] = lam1f[1];
    u[3] = 1.0f; u[4] = lam1f[2]; u[5] = lam1f[3];
    u[6] = 1.0f; u[7] = lam1f[4]; u[8] = lam1f[5];
    float w1[9];      // u_i * Rinv_i
    float D1[3] = {0.0f, 0.0f, 0.0f};   // Lam^T R^-1 Lam (diagonal)
    #pragma unroll
    for (int k = 0; k < 3; ++k) {
        #pragma unroll
        for (int j = 0; j < 3; ++j) {
            int i = 3*k + j;
            w1[i] = u[i] * Rinv[i];
            D1[k] += u[i] * w1[i];
        }
    }
    float Q1[3] = { fabsf(q1d[0]) + 1e-4f, fabsf(q1d[1]) + 1e-4f, fabsf(q1d[2]) + 1e-4f };

    // Regime 2: full B, single-factor loading column
    float B2[9];
    #pragma unroll
    for (int i = 0; i < 9; ++i) B2[i] = b2_in[i];
    float l2[9];
    l2[0] = 1.0f;
    #pragma unroll
    for (int i = 1; i < 9; ++i) l2[i] = lam2f[i-1];
    float w2[9];
    float D200 = 0.0f;     // (Lam2^T R^-1 Lam2)[0,0]; all other entries zero
    #pragma unroll
    for (int i = 0; i < 9; ++i) { w2[i] = l2[i] * Rinv[i]; D200 += l2[i] * w2[i]; }
    float Q2[3] = { fabsf(q2d[0]) + 1e-4f, fabsf(q2d[1]) + 1e-4f, fabsf(q2d[2]) + 1e-4f };

    const float g1 = g1p[0], g3 = g3p[0];
    float g2[3] = { g2p[0], g2p[1], g2p[2] };
    float g4[3] = { g4p[0], g4p[1], g4p[2] };

    // ---------------- per-subject state ----------------
    float e1[3] = {0.0f, 0.0f, 0.0f};
    float e2[3] = {0.0f, 0.0f, 0.0f};
    // symmetric storage: p00,p01,p02,p11,p12,p22
    float P1[6] = {1000.0f, 0.0f, 0.0f, 1000.0f, 0.0f, 1000.0f};
    float P2[6] = {1000.0f, 0.0f, 0.0f, 1000.0f, 0.0f, 1000.0f};
    float m0 = 0.99f, m1 = 0.01f;
    float ll = 0.0f;

    const float* yp = y + (size_t)n * (NTT * OBS);
    float yv[9];
    #pragma unroll
    for (int i = 0; i < 9; ++i) yv[i] = yp[i];

    #pragma unroll 1
    for (int t = 0; t < NTT; ++t) {
        // ---- prefetch next step's observation (hide HBM/L2 latency) ----
        float yn[9];
        const float* ynp = yp + OBS;
        if (t < NTT - 1) {
            #pragma unroll
            for (int i = 0; i < 9; ++i) yn[i] = ynp[i];
        } else {
            #pragma unroll
            for (int i = 0; i < 9; ++i) yn[i] = 0.0f;
        }

        // ---- mixture transition (uses pre-update etas) ----
        float d1 = g1 + e1[0]*g2[0] + e1[1]*g2[1] + e1[2]*g2[2];
        float d2 = g3 + e2[0]*g4[0] + e2[1]*g4[1] + e2[2]*g4[2];
        float p11 = 1.0f / (1.0f + __expf(-d1));
        float p22 = 1.0f / (1.0f + __expf(-d2));
        float mp0 = p11*m0 + (1.0f - p22)*m1;
        float mp1 = (1.0f - p11)*m0 + p22*m1;

        // ================= regime 1 =================
        float ll1;
        {
            float ep0 = b1[0]*e1[0], ep1 = b1[1]*e1[1], ep2 = b1[2]*e1[2];
            float pp00 = b1[0]*b1[0]*P1[0] + Q1[0];
            float pp01 = b1[0]*b1[1]*P1[1];
            float pp02 = b1[0]*b1[2]*P1[2];
            float pp11 = b1[1]*b1[1]*P1[3] + Q1[1];
            float pp12 = b1[1]*b1[2]*P1[4];
            float pp22 = b1[2]*b1[2]*P1[5] + Q1[2];

            float v0 = yv[0] - u[0]*ep0;
            float v1 = yv[1] - u[1]*ep0;
            float v2 = yv[2] - u[2]*ep0;
            float v3 = yv[3] - u[3]*ep1;
            float v4 = yv[4] - u[4]*ep1;
            float v5 = yv[5] - u[5]*ep1;
            float v6 = yv[6] - u[6]*ep2;
            float v7 = yv[7] - u[7]*ep2;
            float v8 = yv[8] - u[8]*ep2;

            float vRv = v0*v0*Rinv[0] + v1*v1*Rinv[1] + v2*v2*Rinv[2]
                      + v3*v3*Rinv[3] + v4*v4*Rinv[4] + v5*v5*Rinv[5]
                      + v6*v6*Rinv[6] + v7*v7*Rinv[7] + v8*v8*Rinv[8];
            float t0 = w1[0]*v0 + w1[1]*v1 + w1[2]*v2;
            float t1 = w1[3]*v3 + w1[4]*v4 + w1[5]*v5;
            float t2 = w1[6]*v6 + w1[7]*v7 + w1[8]*v8;

            // Pinv via adjugate
            float c00 = pp11*pp22 - pp12*pp12;
            float c01 = pp02*pp12 - pp01*pp22;
            float c02 = pp01*pp12 - pp02*pp11;
            float c11 = pp00*pp22 - pp02*pp02;
            float c12 = pp01*pp02 - pp00*pp12;
            float c22 = pp00*pp11 - pp01*pp01;
            float detP = pp00*c00 + pp01*c01 + pp02*c02;
            float idet = 1.0f / detP;

            // S = Pinv + D1 (diag)
            float s00 = c00*idet + D1[0];
            float s01 = c01*idet;
            float s02 = c02*idet;
            float s11 = c11*idet + D1[1];
            float s12 = c12*idet;
            float s22 = c22*idet + D1[2];

            float E00 = s11*s22 - s12*s12;
            float E01 = s02*s12 - s01*s22;
            float E02 = s01*s12 - s02*s11;
            float E11 = s00*s22 - s02*s02;
            float E12 = s01*s02 - s00*s12;
            float E22 = s00*s11 - s01*s01;
            float detS = s00*E00 + s01*E01 + s02*E02;
            float idetS = 1.0f / detS;

            float x0 = (E00*t0 + E01*t1 + E02*t2) * idetS;
            float x1 = (E01*t0 + E11*t1 + E12*t2) * idetS;
            float x2 = (E02*t0 + E12*t1 + E22*t2) * idetS;
            float quad = t0*x0 + t1*x1 + t2*x2;

            ll1 = -0.5f * (9.0f*LOG2PI + logdetR + __logf(detP*detS) + vRv - quad);

            e1[0] = ep0 + x0; e1[1] = ep1 + x1; e1[2] = ep2 + x2;
            P1[0] = E00*idetS; P1[1] = E01*idetS; P1[2] = E02*idetS;
            P1[3] = E11*idetS; P1[4] = E12*idetS; P1[5] = E22*idetS;
        }

        // ================= regime 2 =================
        float ll2;
        {
            float f0 = B2[0]*e2[0] + B2[1]*e2[1] + B2[2]*e2[2];
            float f1 = B2[3]*e2[0] + B2[4]*e2[1] + B2[5]*e2[2];
            float f2 = B2[6]*e2[0] + B2[7]*e2[1] + B2[8]*e2[2];

            // M = B2 * P2 (P2 symmetric)
            float M00 = B2[0]*P2[0] + B2[1]*P2[1] + B2[2]*P2[2];
            float M01 = B2[0]*P2[1] + B2[1]*P2[3] + B2[2]*P2[4];
            float M02 = B2[0]*P2[2] + B2[1]*P2[4] + B2[2]*P2[5];
            float M10 = B2[3]*P2[0] + B2[4]*P2[1] + B2[5]*P2[2];
            float M11 = B2[3]*P2[1] + B2[4]*P2[3] + B2[5]*P2[4];
            float M12 = B2[3]*P2[2] + B2[4]*P2[4] + B2[5]*P2[5];
            float M20 = B2[6]*P2[0] + B2[7]*P2[1] + B2[8]*P2[2];
            float M21 = B2[6]*P2[1] + B2[7]*P2[3] + B2[8]*P2[4];
            float M22 = B2[6]*P2[2] + B2[7]*P2[4] + B2[8]*P2[5];

            // Pp = M * B2^T + Q2 (symmetric part)
            float pp00 = M00*B2[0] + M01*B2[1] + M02*B2[2] + Q2[0];
            float pp01 = M00*B2[3] + M01*B2[4] + M02*B2[5];
            float pp02 = M00*B2[6] + M01*B2[7] + M02*B2[8];
            float pp11 = M10*B2[3] + M11*B2[4] + M12*B2[5] + Q2[1];
            float pp12 = M10*B2[6] + M11*B2[7] + M12*B2[8];
            float pp22 = M20*B2[6] + M21*B2[7] + M22*B2[8] + Q2[2];

            float v0 = yv[0] - l2[0]*f0;
            float v1 = yv[1] - l2[1]*f0;
            float v2 = yv[2] - l2[2]*f0;
            float v3 = yv[3] - l2[3]*f0;
            float v4 = yv[4] - l2[4]*f0;
            float v5 = yv[5] - l2[5]*f0;
            float v6 = yv[6] - l2[6]*f0;
            float v7 = yv[7] - l2[7]*f0;
            float v8 = yv[8] - l2[8]*f0;

            float vRv = v0*v0*Rinv[0] + v1*v1*Rinv[1] + v2*v2*Rinv[2]
                      + v3*v3*Rinv[3] + v4*v4*Rinv[4] + v5*v5*Rinv[5]
                      + v6*v6*Rinv[6] + v7*v7*Rinv[7] + v8*v8*Rinv[8];
            float tt0 = w2[0]*v0 + w2[1]*v1 + w2[2]*v2
                      + w2[3]*v3 + w2[4]*v4 + w2[5]*v5
                      + w2[6]*v6 + w2[7]*v7 + w2[8]*v8;

            float c00 = pp11*pp22 - pp12*pp12;
            float c01 = pp02*pp12 - pp01*pp22;
            float c02 = pp01*pp12 - pp02*pp11;
            float c11 = pp00*pp22 - pp02*pp02;
            float c12 = pp01*pp02 - pp00*pp12;
            float c22 = pp00*pp11 - pp01*pp01;
            float detP = pp00*c00 + pp01*c01 + pp02*c02;
            float idet = 1.0f / detP;

            float s00 = c00*idet + D200;   // only [0,0] gets observation info
            float s01 = c01*idet;
            float s02 = c02*idet;
            float s11 = c11*idet;
            float s12 = c12*idet;
            float s22 = c22*idet;

            float E00 = s11*s22 - s12*s12;
            float E01 = s02*s12 - s01*s22;
            float E02 = s01*s12 - s02*s11;
            float E11 = s00*s22 - s02*s02;
            float E12 = s01*s02 - s00*s12;
            float E22 = s00*s11 - s01*s01;
            float detS = s00*E00 + s01*E01 + s02*E02;
            float idetS = 1.0f / detS;

            float x0 = E00*tt0*idetS;
            float x1 = E01*tt0*idetS;
            float x2 = E02*tt0*idetS;
            float quad = tt0*x0;

            ll2 = -0.5f * (9.0f*LOG2PI + logdetR + __logf(detP*detS) + vRv - quad);

            e2[0] = f0 + x0; e2[1] = f1 + x1; e2[2] = f2 + x2;
            P2[0] = E00*idetS; P2[1] = E01*idetS; P2[2] = E02*idetS;
            P2[3] = E11*idetS; P2[4] = E12*idetS; P2[5] = E22*idetS;
        }

        // ---- mixture update (log-space) ----
        float lj0 = ll1 + __logf(mp0 + 1e-9f);
        float lj1 = ll2 + __logf(mp1 + 1e-9f);
        float mx = fmaxf(lj0, lj1);
        float ea = __expf(lj0 - mx);
        float eb = __expf(lj1 - mx);
        float ssum = ea + eb;
        float lm = mx + __logf(ssum);
        float isum = 1.0f / ssum;
        m0 = ea * isum;
        m1 = eb * isum;
        ll += lm;

        // rotate prefetched observation into place
        #pragma unroll
        for (int i = 0; i < 9; ++i) yv[i] = yn[i];
        yp = ynp;
    }

    // ---- wave (=block) reduction, one atomic per block ----
    float v = ll;
    v += __shfl_down(v, 32);
    v += __shfl_down(v, 16);
    v += __shfl_down(v, 8);
    v += __shfl_down(v, 4);
    v += __shfl_down(v, 2);
    v += __shfl_down(v, 1);
    if (threadIdx.x == 0) atomicAdd(out, -v);
}

extern "C" void kernel_launch(void* const* d_in, const int* in_sizes, int n_in,
                              void* d_out, int out_size, void* d_ws, size_t ws_size,
                              hipStream_t stream) {
    const float* y      = (const float*)d_in[0];
    const float* b1_r1  = (const float*)d_in[1];
    const float* lam1f  = (const float*)d_in[2];
    const float* q1d    = (const float*)d_in[3];
    const float* b2     = (const float*)d_in[4];
    const float* lam2f  = (const float*)d_in[5];
    const float* q2d    = (const float*)d_in[6];
    const float* r_in   = (const float*)d_in[7];
    const float* g1     = (const float*)d_in[8];
    const float* g2     = (const float*)d_in[9];
    const float* g3     = (const float*)d_in[10];
    const float* g4     = (const float*)d_in[11];
    float* out = (float*)d_out;

    hipLaunchKernelGGL(zero_out_kernel, dim3(1), dim3(1), 0, stream, out);
    hipLaunchKernelGGL(rskf_kernel, dim3(NSUBJ / 64), dim3(64), 0, stream,
                       y, b1_r1, lam1f, q1d, b2, lam2f, q2d, r_in,
                       g1, g2, g3, g4, out);
}

// Round 2
// 517.722 us; speedup vs baseline: 1.3198x; 1.3198x over previous
//
#include <hip/hip_runtime.h>
#include <math.h>

#define NSUBJ 8192
#define NTT   512
#define OBS   9
#define LOG2PI 1.8378770664093453f

__global__ void zero_out_kernel(float* out) { out[0] = 0.0f; }

// Two lanes per subject: even lane = regime 1, odd lane = regime 2.
// Unified arithmetic via per-lane constants (no exec-mask divergence).
__global__ __launch_bounds__(64, 1) void rskf_kernel(
    const float* __restrict__ y,        // (N, NT, O)
    const float* __restrict__ b1_r1,    // (3,)
    const float* __restrict__ lam1f,    // (6,)
    const float* __restrict__ q1d,      // (3,)
    const float* __restrict__ b2_in,    // (3,3) row-major
    const float* __restrict__ lam2f,    // (8,)
    const float* __restrict__ q2d,      // (3,)
    const float* __restrict__ r_in,     // (9,)
    const float* __restrict__ g1p,      // (1,)
    const float* __restrict__ g2p,      // (3,)
    const float* __restrict__ g3p,      // (1,)
    const float* __restrict__ g4p,      // (3,)
    float* __restrict__ out)
{
    const int tid  = blockIdx.x * 64 + threadIdx.x;
    const int subj = tid >> 1;
    const bool is2 = (tid & 1) != 0;          // odd lane -> regime 2

    // ---------- uniform constants (stay in SGPRs) ----------
    float Rinv[9];
    float logdetR = 0.0f;
    #pragma unroll
    for (int i = 0; i < 9; ++i) {
        float r = fabsf(r_in[i]) + 1e-4f;
        Rinv[i] = 1.0f / r;
        logdetR += __logf(r);
    }
    const float C0 = 9.0f * LOG2PI + logdetR;

    // ---------- per-lane (regime-selected) constants ----------
    // Transition matrix: regime1 = diag(b1), regime2 = full B2
    float Bm[9];
    {
        float a0 = b1_r1[0], a1 = b1_r1[1], a2 = b1_r1[2];
        Bm[0] = is2 ? b2_in[0] : a0;
        Bm[1] = is2 ? b2_in[1] : 0.0f;
        Bm[2] = is2 ? b2_in[2] : 0.0f;
        Bm[3] = is2 ? b2_in[3] : 0.0f;
        Bm[4] = is2 ? b2_in[4] : a1;
        Bm[5] = is2 ? b2_in[5] : 0.0f;
        Bm[6] = is2 ? b2_in[6] : 0.0f;
        Bm[7] = is2 ? b2_in[7] : 0.0f;
        Bm[8] = is2 ? b2_in[8] : a2;
    }
    // Loading magnitudes: regime1 3-factor (u), regime2 single column (l2).
    float lam[9];
    lam[0] = 1.0f;
    lam[1] = is2 ? lam2f[0] : lam1f[0];
    lam[2] = is2 ? lam2f[1] : lam1f[1];
    lam[3] = is2 ? lam2f[2] : 1.0f;
    lam[4] = is2 ? lam2f[3] : lam1f[2];
    lam[5] = is2 ? lam2f[4] : lam1f[3];
    lam[6] = is2 ? lam2f[5] : 1.0f;
    lam[7] = is2 ? lam2f[6] : lam1f[4];
    lam[8] = is2 ? lam2f[7] : lam1f[5];

    // D = Lam^T R^-1 Lam : diagonal in both regimes' effective basis.
    float dA = lam[0]*lam[0]*Rinv[0] + lam[1]*lam[1]*Rinv[1] + lam[2]*lam[2]*Rinv[2];
    float dB = lam[3]*lam[3]*Rinv[3] + lam[4]*lam[4]*Rinv[4] + lam[5]*lam[5]*Rinv[5];
    float dC = lam[6]*lam[6]*Rinv[6] + lam[7]*lam[7]*Rinv[7] + lam[8]*lam[8]*Rinv[8];
    float Dd0 = is2 ? (dA + dB + dC) : dA;
    float Dd1 = is2 ? 0.0f : dB;
    float Dd2 = is2 ? 0.0f : dC;

    float Q0 = fabsf(is2 ? q2d[0] : q1d[0]) + 1e-4f;
    float Q1 = fabsf(is2 ? q2d[1] : q1d[1]) + 1e-4f;
    float Q2 = fabsf(is2 ? q2d[2] : q1d[2]) + 1e-4f;

    const float gs  = is2 ? g3p[0] : g1p[0];
    float gv[3] = { is2 ? g4p[0] : g2p[0],
                    is2 ? g4p[1] : g2p[1],
                    is2 ? g4p[2] : g2p[2] };

    // ---------- per-lane state ----------
    float e0 = 0.0f, e1 = 0.0f, e2 = 0.0f;
    float P0 = 1000.0f, P1s = 0.0f, P2s = 0.0f, P3 = 1000.0f, P4 = 0.0f, P5 = 1000.0f;
    float mA = is2 ? 0.01f : 0.99f;   // own-regime prob
    float mB = is2 ? 0.99f : 0.01f;   // other-regime prob
    float llacc = 0.0f;

    const float* ybase = y + (size_t)subj * (NTT * OBS);
    float ya[9], yb[9];
    #pragma unroll
    for (int j = 0; j < 9; ++j) { ya[j] = ybase[j]; yb[j] = ybase[9 + j]; }

    auto step = [&](float (&buf)[9], const float* ld, bool doload) {
        // ---- mixture transition (uses pre-update eta) ----
        float d   = gs + e0*gv[0] + e1*gv[1] + e2*gv[2];
        float sig = 1.0f / (1.0f + __expf(-d));      // own self-stay prob
        float oth = __shfl_xor(sig, 1);               // other regime's self-stay
        float mp  = sig * mA + (1.0f - oth) * mB;     // own predicted prob

        // ---- state/cov prediction ----
        float ep0 = Bm[0]*e0 + Bm[1]*e1 + Bm[2]*e2;
        float ep1 = Bm[3]*e0 + Bm[4]*e1 + Bm[5]*e2;
        float ep2 = Bm[6]*e0 + Bm[7]*e1 + Bm[8]*e2;
        // factor attached to obs i: regime1 -> ep[i/3], regime2 -> ep0
        float es1 = is2 ? ep0 : ep1;
        float es2 = is2 ? ep0 : ep2;

        float v0 = buf[0] - lam[0]*ep0;
        float v1 = buf[1] - lam[1]*ep0;
        float v2 = buf[2] - lam[2]*ep0;
        float v3 = buf[3] - lam[3]*es1;
        float v4 = buf[4] - lam[4]*es1;
        float v5 = buf[5] - lam[5]*es1;
        float v6 = buf[6] - lam[6]*es2;
        float v7 = buf[7] - lam[7]*es2;
        float v8 = buf[8] - lam[8]*es2;

        // ---- buf consumed: issue prefetch for t+2 ----
        if (doload) {
            #pragma unroll
            for (int j = 0; j < 9; ++j) buf[j] = ld[j];
        } else {
            #pragma unroll
            for (int j = 0; j < 9; ++j) buf[j] = 0.0f;
        }

        float vr0 = v0*Rinv[0], vr1 = v1*Rinv[1], vr2 = v2*Rinv[2];
        float vr3 = v3*Rinv[3], vr4 = v4*Rinv[4], vr5 = v5*Rinv[5];
        float vr6 = v6*Rinv[6], vr7 = v7*Rinv[7], vr8 = v8*Rinv[8];
        float vRv = v0*vr0 + v1*vr1 + v2*vr2 + v3*vr3 + v4*vr4
                  + v5*vr5 + v6*vr6 + v7*vr7 + v8*vr8;

        float pA = lam[0]*vr0 + lam[1]*vr1 + lam[2]*vr2;
        float pB = lam[3]*vr3 + lam[4]*vr4 + lam[5]*vr5;
        float pC = lam[6]*vr6 + lam[7]*vr7 + lam[8]*vr8;
        float t0 = is2 ? (pA + pB + pC) : pA;
        float t1 = is2 ? 0.0f : pB;
        float t2 = is2 ? 0.0f : pC;

        // Pp = Bm * P * Bm^T + Q   (P symmetric)
        float M00 = Bm[0]*P0  + Bm[1]*P1s + Bm[2]*P2s;
        float M01 = Bm[0]*P1s + Bm[1]*P3  + Bm[2]*P4;
        float M02 = Bm[0]*P2s + Bm[1]*P4  + Bm[2]*P5;
        float M10 = Bm[3]*P0  + Bm[4]*P1s + Bm[5]*P2s;
        float M11 = Bm[3]*P1s + Bm[4]*P3  + Bm[5]*P4;
        float M12 = Bm[3]*P2s + Bm[4]*P4  + Bm[5]*P5;
        float M20 = Bm[6]*P0  + Bm[7]*P1s + Bm[8]*P2s;
        float M21 = Bm[6]*P1s + Bm[7]*P3  + Bm[8]*P4;
        float M22 = Bm[6]*P2s + Bm[7]*P4  + Bm[8]*P5;

        float pp00 = M00*Bm[0] + M01*Bm[1] + M02*Bm[2] + Q0;
        float pp01 = M00*Bm[3] + M01*Bm[4] + M02*Bm[5];
        float pp02 = M00*Bm[6] + M01*Bm[7] + M02*Bm[8];
        float pp11 = M10*Bm[3] + M11*Bm[4] + M12*Bm[5] + Q1;
        float pp12 = M10*Bm[6] + M11*Bm[7] + M12*Bm[8];
        float pp22 = M20*Bm[6] + M21*Bm[7] + M22*Bm[8] + Q2;

        // Pp^-1 via adjugate
        float c00 = pp11*pp22 - pp12*pp12;
        float c01 = pp02*pp12 - pp01*pp22;
        float c02 = pp01*pp12 - pp02*pp11;
        float c11 = pp00*pp22 - pp02*pp02;
        float c12 = pp01*pp02 - pp00*pp12;
        float c22 = pp00*pp11 - pp01*pp01;
        float detP = pp00*c00 + pp01*c01 + pp02*c02;
        float idet = 1.0f / detP;

        // S = Pp^-1 + D (diagonal D)
        float s00 = c00*idet + Dd0;
        float s01 = c01*idet;
        float s02 = c02*idet;
        float s11 = c11*idet + Dd1;
        float s12 = c12*idet;
        float s22 = c22*idet + Dd2;

        float E00 = s11*s22 - s12*s12;
        float E01 = s02*s12 - s01*s22;
        float E02 = s01*s12 - s02*s11;
        float E11 = s00*s22 - s02*s02;
        float E12 = s01*s02 - s00*s12;
        float E22 = s00*s11 - s01*s01;
        float detS = s00*E00 + s01*E01 + s02*E02;
        float idetS = 1.0f / detS;

        float x0 = (E00*t0 + E01*t1 + E02*t2) * idetS;
        float x1 = (E01*t0 + E11*t1 + E12*t2) * idetS;
        float x2 = (E02*t0 + E12*t1 + E22*t2) * idetS;
        float quad = t0*x0 + t1*x1 + t2*x2;

        float llo = -0.5f * (C0 + __logf(detP*detS) + vRv - quad);

        e0 = ep0 + x0; e1 = ep1 + x1; e2 = ep2 + x2;
        P0 = E00*idetS; P1s = E01*idetS; P2s = E02*idetS;
        P3 = E11*idetS; P4  = E12*idetS; P5  = E22*idetS;

        // ---- mixture update (log-space), duplicated on both lanes ----
        float lj  = llo + __logf(mp + 1e-9f);
        float ljo = __shfl_xor(lj, 1);
        float mx  = fmaxf(lj, ljo);
        float ea  = __expf(lj - mx);
        float eb  = __expf(ljo - mx);
        float ssum = ea + eb;
        float isum = 1.0f / ssum;
        llacc += mx + __logf(ssum);
        mA = ea * isum;
        mB = eb * isum;
    };

    const float* pl = ybase + 18;   // t+2 stream
    #pragma unroll 1
    for (int t = 0; t < NTT; t += 2) {
        step(ya, pl,     t + 2 < NTT);
        step(yb, pl + 9, t + 3 < NTT);
        pl += 18;
    }

    // ---- wave reduction; each pair double-counts lm -> scale 0.5 ----
    float v = llacc;
    v += __shfl_down(v, 32);
    v += __shfl_down(v, 16);
    v += __shfl_down(v, 8);
    v += __shfl_down(v, 4);
    v += __shfl_down(v, 2);
    v += __shfl_down(v, 1);
    if (threadIdx.x == 0) atomicAdd(out, -0.5f * v);
}

extern "C" void kernel_launch(void* const* d_in, const int* in_sizes, int n_in,
                              void* d_out, int out_size, void* d_ws, size_t ws_size,
                              hipStream_t stream) {
    const float* y      = (const float*)d_in[0];
    const float* b1_r1  = (const float*)d_in[1];
    const float* lam1f  = (const float*)d_in[2];
    const float* q1d    = (const float*)d_in[3];
    const float* b2     = (const float*)d_in[4];
    const float* lam2f  = (const float*)d_in[5];
    const float* q2d    = (const float*)d_in[6];
    const float* r_in   = (const float*)d_in[7];
    const float* g1     = (const float*)d_in[8];
    const float* g2     = (const float*)d_in[9];
    const float* g3     = (const float*)d_in[10];
    const float* g4     = (const float*)d_in[11];
    float* out = (float*)d_out;

    hipLaunchKernelGGL(zero_out_kernel, dim3(1), dim3(1), 0, stream, out);
    hipLaunchKernelGGL(rskf_kernel, dim3((NSUBJ * 2) / 64), dim3(64), 0, stream,
                       y, b1_r1, lam1f, q1d, b2, lam2f, q2d, r_in,
                       g1, g2, g3, g4, out);
}